// Round 5
// baseline (17.531 us; speedup 1.0000x reference)
//
#include <hip/hip_runtime.h>

// x: (8,512,1024) f32 -> 4096 rows of 1024.  out: (8,512,16) f32.
// Ops (states real): o=0..9 Z on bit (9-o) -> signed sum of squares;
//   o=10..12 X with flip mask 512/256/128 -> 2*sum_{d:bit=0} x[d]x[d^m];
//   o=13..15 single Y on real state -> exactly 0.
//
// 16-LANE GROUP per row (4 rows per wave). Lane = g*16 + l4, row = base + g.
// Element d = r*64 + l4*4 + c   (r = d[9:6] register index, l4 = d[5:2], c = d[1:0]).
// All X masks (512,256,128) are r-bits -> zero cross-lane X work.
// Reduction: 4-stage xor reduce-scatter within the 16-lane group; lane l4
// finishes holding op l4 of its row -> all 64 lanes store one dword, coalesced.
__global__ __launch_bounds__(256) void pauli_exp_q(const float* __restrict__ x,
                                                   float* __restrict__ out) {
    const int lane = threadIdx.x & 63;
    const int l4   = lane & 15;
    const int row  = blockIdx.x * 16 + ((threadIdx.x >> 6) << 2) + (lane >> 4);

    const float4* rp = reinterpret_cast<const float4*>(x) + (size_t)row * 256;
    float4 v[16];
#pragma unroll
    for (int r = 0; r < 16; ++r) v[r] = rp[r * 16 + l4];

    // squares: t[r] = |v_r|^2 ; A (c bit1), B (c bit0) component-sign sums
    float t[16], A = 0.f, B = 0.f;
#pragma unroll
    for (int r = 0; r < 16; ++r) {
        const float sx = v[r].x * v[r].x;
        const float sy = v[r].y * v[r].y;
        const float sz = v[r].z * v[r].z;
        const float sw = v[r].w * v[r].w;
        t[r] = (sx + sy) + (sz + sw);
        A += (sx + sy) - (sz + sw);          // op8: Z bit1
        B += (sx - sy) + (sz - sw);          // op9: Z bit0
    }

    // Z on r-bits 3..0 (ops 0..3) and total S
    float op0 = 0.f, op1 = 0.f, op2 = 0.f, op3 = 0.f, S = 0.f;
#pragma unroll
    for (int r = 0; r < 16; ++r) {
        S += t[r];
        op0 += (r & 8) ? -t[r] : t[r];       // op0: Z bit9
        op1 += (r & 4) ? -t[r] : t[r];       // op1: Z bit8
        op2 += (r & 2) ? -t[r] : t[r];       // op2: Z bit7
        op3 += (r & 1) ? -t[r] : t[r];       // op3: Z bit6
    }

    // Z on l4-bits 3..0 (ops 4..7): per-lane sign on S
    const float op4 = (l4 & 8) ? -S : S;     // Z bit5
    const float op5 = (l4 & 4) ? -S : S;     // Z bit4
    const float op6 = (l4 & 2) ? -S : S;     // Z bit3
    const float op7 = (l4 & 1) ? -S : S;     // Z bit2

    // X correlations: register-pair dots on r-bit flips
    auto dot4 = [](const float4& a, const float4& b) {
        return (a.x * b.x + a.y * b.y) + (a.z * b.z + a.w * b.w);
    };
    float x512 = 0.f, x256 = 0.f, x128 = 0.f;
#pragma unroll
    for (int r = 0; r < 8; ++r) x512 += dot4(v[r], v[r + 8]);        // flip r bit3
#pragma unroll
    for (int r = 0; r < 16; ++r) if (!(r & 4)) x256 += dot4(v[r], v[r | 4]); // flip r bit2
#pragma unroll
    for (int r = 0; r < 16; ++r) if (!(r & 2)) x128 += dot4(v[r], v[r | 2]); // flip r bit1
    x512 *= 2.f; x256 *= 2.f; x128 *= 2.f;

    // 4-stage reduce-scatter within the 16-lane group: lane l4 ends with w[l4]
    float w[16] = {op0, op1, op2, op3, op4, op5, op6, op7, A, B,
                   x512, x256, x128, 0.f, 0.f, 0.f};
    float w8[8];
    {
        const bool hi = lane & 1;
#pragma unroll
        for (int i = 0; i < 8; ++i) {
            const float keep = hi ? w[2 * i + 1] : w[2 * i];
            const float send = hi ? w[2 * i]     : w[2 * i + 1];
            w8[i] = keep + __shfl_xor(send, 1, 64);
        }
    }
    float w4[4];
    {
        const bool hi = lane & 2;
#pragma unroll
        for (int i = 0; i < 4; ++i) {
            const float keep = hi ? w8[2 * i + 1] : w8[2 * i];
            const float send = hi ? w8[2 * i]     : w8[2 * i + 1];
            w4[i] = keep + __shfl_xor(send, 2, 64);
        }
    }
    float w2[2];
    {
        const bool hi = lane & 4;
#pragma unroll
        for (int i = 0; i < 2; ++i) {
            const float keep = hi ? w4[2 * i + 1] : w4[2 * i];
            const float send = hi ? w4[2 * i]     : w4[2 * i + 1];
            w2[i] = keep + __shfl_xor(send, 4, 64);
        }
    }
    float a;
    {
        const bool hi = lane & 8;
        const float keep = hi ? w2[1] : w2[0];
        const float send = hi ? w2[0] : w2[1];
        a = keep + __shfl_xor(send, 8, 64);
    }
    // lane l4 now holds op l4 summed over its row's 16 lanes (13..15 = 0)

    out[(size_t)row * 16 + l4] = a;   // 64 dwords/wave, contiguous across 4 rows
}

extern "C" void kernel_launch(void* const* d_in, const int* in_sizes, int n_in,
                              void* d_out, int out_size, void* d_ws, size_t ws_size,
                              hipStream_t stream) {
    const float* x = (const float*)d_in[0];
    float* out = (float*)d_out;
    const int n_rows = in_sizes[0] / 1024;     // 4096
    pauli_exp_q<<<n_rows / 16, 256, 0, stream>>>(x, out);
}

// Round 6
// 9.410 us; speedup vs baseline: 1.8630x; 1.8630x over previous
//
#include <hip/hip_runtime.h>

// x: (8,512,1024) f32 -> 4096 rows of 1024.  out: (8,512,16) f32.
// Ops (states real): o=0..9 Z on bit (9-o) -> signed sum of squares;
//   o=10..12 X with flip mask 512/256/128 -> 2*correlation;
//   o=13..15 single Y on real state -> exactly 0.
//
// HALF-WAVE per row: lanes [0,32) -> row base, lanes [32,64) -> base+1.
// Element d = r*128 + l5*4 + c  (r = d[9:7] register index, l5 = d[6:2] = lane&31,
// c = d[1:0] within float4). All X flip masks (512,256,128) are register-index
// bits -> zero cross-lane X work. Occupancy: 512 blocks = 2/CU, 8 waves/CU.
__global__ __launch_bounds__(256) void pauli_exp_half(const float* __restrict__ x,
                                                      float* __restrict__ out) {
    const int wave = threadIdx.x >> 6;
    const int lane = threadIdx.x & 63;
    const int l5   = lane & 31;
    const int row  = blockIdx.x * 8 + wave * 2 + (lane >> 5);   // 0..4095

    const float4* rp = reinterpret_cast<const float4*>(x) + (size_t)row * 256;
    float4 v[8];
#pragma unroll
    for (int r = 0; r < 8; ++r) v[r] = rp[r * 32 + l5];

    // per-register squares: t[r] = |v_r|^2, A/B = component-sign sums (bits 1,0)
    float t[8], A = 0.f, B = 0.f;
#pragma unroll
    for (int r = 0; r < 8; ++r) {
        const float sx = v[r].x * v[r].x;
        const float sy = v[r].y * v[r].y;
        const float sz = v[r].z * v[r].z;
        const float sw = v[r].w * v[r].w;
        t[r] = (sx + sy) + (sz + sw);
        A += (sx + sy) - (sz + sw);      // op8: Z bit1 (c bit1)
        B += (sx - sy) + (sz - sw);      // op9: Z bit0 (c bit0)
    }
    const float t03 = (t[0] + t[1]) + (t[2] + t[3]);
    const float t47 = (t[4] + t[5]) + (t[6] + t[7]);
    const float S   = t03 + t47;
    const float z9  = t03 - t47;                                          // op0 (r bit2)
    const float z8  = ((t[0] + t[1]) + (t[4] + t[5])) - ((t[2] + t[3]) + (t[6] + t[7])); // op1
    const float z7  = ((t[0] + t[2]) + (t[4] + t[6])) - ((t[1] + t[3]) + (t[5] + t[7])); // op2

    // ops 3..7: Z on d-bits 6..2 = l5 bits 4..0 -> per-lane sign on S
    const float z6 = (l5 & 16) ? -S : S;
    const float z5 = (l5 & 8)  ? -S : S;
    const float z4 = (l5 & 4)  ? -S : S;
    const float z3 = (l5 & 2)  ? -S : S;
    const float z2 = (l5 & 1)  ? -S : S;

    // X correlations: register-pair dots (flip = register-index bit)
    auto dot4 = [](const float4& a, const float4& b) {
        return (a.x * b.x + a.y * b.y) + (a.z * b.z + a.w * b.w);
    };
    const float x512 = 2.f * ((dot4(v[0], v[4]) + dot4(v[1], v[5])) +
                              (dot4(v[2], v[6]) + dot4(v[3], v[7])));   // op10 (bit9)
    const float x256 = 2.f * ((dot4(v[0], v[2]) + dot4(v[1], v[3])) +
                              (dot4(v[4], v[6]) + dot4(v[5], v[7])));   // op11 (bit8)
    const float x128 = 2.f * ((dot4(v[0], v[1]) + dot4(v[2], v[3])) +
                              (dot4(v[4], v[5]) + dot4(v[6], v[7])));   // op12 (bit7)

    // 16-value reduce-scatter within each 32-lane half: xor 1,2,4,8 halving
    // stages leave lane l holding w[l&15] summed over its 16-group; xor 16
    // completes the 32-lane (one-row) sum. No xor-32 (that would mix rows).
    float w[16] = {z9, z8, z7, z6, z5, z4, z3, z2, A, B,
                   x512, x256, x128, 0.f, 0.f, 0.f};
    float w8[8];
    {
        const bool hi = lane & 1;
#pragma unroll
        for (int i = 0; i < 8; ++i) {
            const float keep = hi ? w[2 * i + 1] : w[2 * i];
            const float send = hi ? w[2 * i]     : w[2 * i + 1];
            w8[i] = keep + __shfl_xor(send, 1, 64);
        }
    }
    float w4[4];
    {
        const bool hi = lane & 2;
#pragma unroll
        for (int i = 0; i < 4; ++i) {
            const float keep = hi ? w8[2 * i + 1] : w8[2 * i];
            const float send = hi ? w8[2 * i]     : w8[2 * i + 1];
            w4[i] = keep + __shfl_xor(send, 2, 64);
        }
    }
    float w2[2];
    {
        const bool hi = lane & 4;
#pragma unroll
        for (int i = 0; i < 2; ++i) {
            const float keep = hi ? w4[2 * i + 1] : w4[2 * i];
            const float send = hi ? w4[2 * i]     : w4[2 * i + 1];
            w2[i] = keep + __shfl_xor(send, 4, 64);
        }
    }
    float a;
    {
        const bool hi = lane & 8;
        const float keep = hi ? w2[1] : w2[0];
        const float send = hi ? w2[0] : w2[1];
        a = keep + __shfl_xor(send, 8, 64);
    }
    a += __shfl_xor(a, 16, 64);   // completes the per-row sum

    if (l5 < 16) out[(size_t)row * 16 + l5] = a;   // lane l5 holds op l5; 13..15 = 0
}

extern "C" void kernel_launch(void* const* d_in, const int* in_sizes, int n_in,
                              void* d_out, int out_size, void* d_ws, size_t ws_size,
                              hipStream_t stream) {
    const float* x = (const float*)d_in[0];
    float* out = (float*)d_out;
    const int n_rows = in_sizes[0] / 1024;        // 4096
    pauli_exp_half<<<n_rows / 8, 256, 0, stream>>>(x, out);
}